// Round 2
// baseline (58.773 us; speedup 1.0000x reference)
//
#include <hip/hip_runtime.h>
#include <math.h>

#define DIM 256
#define NLAYERS 64

typedef __attribute__((ext_vector_type(8))) short short8;
typedef __attribute__((ext_vector_type(4))) float f32x4;

// ---------- helpers ----------

// DPP wave-wide shifts (verified in R1).
__device__ __forceinline__ float dpp_shl1_zero(float v) {
    int r = __builtin_amdgcn_update_dpp(0, __float_as_int(v), 0x130, 0xF, 0xF, true);
    return __int_as_float(r);
}
__device__ __forceinline__ float dpp_shr1_keep(float oldv, float v) {
    int r = __builtin_amdgcn_update_dpp(__float_as_int(oldv), __float_as_int(v), 0x138, 0xF, 0xF, false);
    return __int_as_float(r);
}

// f32 -> bf16 bits, round-to-nearest-even (inputs are finite, well-scaled).
__device__ __forceinline__ unsigned short f2bf(float f) {
    unsigned u = __float_as_uint(f);
    u += 0x7FFFu + ((u >> 16) & 1u);
    return (unsigned short)(u >> 16);
}

// ---------- kernel 1: build M^T (bf16) from theta ----------
// Pushes identity rows through the 64 layers (same machinery as the verified
// direct kernel), producing M with out = x @ M.  Stores MT[col][k] = M[k][col]
// so GEMM B-fragments are contiguous 16B loads.
__global__ __launch_bounds__(256)
void build_m_kernel(const float* __restrict__ theta, unsigned short* __restrict__ mt) {
    __shared__ float tbl[NLAYERS * DIM];  // 64 KB: [ (l*128+p)*2 + {c,s} ]

    const int tid = threadIdx.x;
    #pragma unroll
    for (int k = 0; k < 32; ++k) {
        int idx = tid + 256 * k;          // idx = l*128 + p
        int l = idx >> 7;
        int p = idx & 127;
        float s, c;
        sincosf(2.0f * theta[idx], &s, &c);
        if ((l & 1) && (p == 127)) { c = 1.0f; s = 0.0f; }  // odd-layer pass-through pair
        tbl[idx * 2 + 0] = c;
        tbl[idx * 2 + 1] = s;
    }
    __syncthreads();

    const int w = tid >> 6;
    const int t = tid & 63;
    const int row0 = blockIdx.x * 8 + w * 2;   // 2 identity rows per wave

    float e[2][4];
    #pragma unroll
    for (int r = 0; r < 2; ++r)
        #pragma unroll
        for (int j = 0; j < 4; ++j)
            e[r][j] = (4 * t + j == row0 + r) ? 1.0f : 0.0f;

    const float4* tbl4 = (const float4*)tbl;
    #pragma unroll 2
    for (int l = 0; l < NLAYERS; l += 2) {
        float4 cs = tbl4[(l << 6) + t];
        #pragma unroll
        for (int r = 0; r < 2; ++r) {
            float a0 = e[r][0], a1 = e[r][1], a2 = e[r][2], a3 = e[r][3];
            e[r][0] = cs.x * a0 + cs.y * a1;
            e[r][1] = cs.y * a0 - cs.x * a1;
            e[r][2] = cs.z * a2 + cs.w * a3;
            e[r][3] = cs.w * a2 - cs.z * a3;
        }
        float4 cs1 = tbl4[((l + 1) << 6) + t];
        #pragma unroll
        for (int r = 0; r < 2; ++r) {
            float a1 = e[r][1], a2 = e[r][2], a3 = e[r][3];
            float n1 = cs1.x * a1 + cs1.y * a2;
            float n2 = cs1.y * a1 - cs1.x * a2;
            float xjn = dpp_shl1_zero(e[r][0]);
            float n3  = cs1.z * a3 + cs1.w * xjn;
            float snd = cs1.w * a3 - cs1.z * xjn;
            e[r][0] = dpp_shr1_keep(e[r][0], snd);
            e[r][1] = n1; e[r][2] = n2; e[r][3] = n3;
        }
    }

    // row (row0+r) of M holds M[row0+r][4t+j]; store transposed as bf16.
    #pragma unroll
    for (int r = 0; r < 2; ++r)
        #pragma unroll
        for (int j = 0; j < 4; ++j)
            mt[(4 * t + j) * 256 + (row0 + r)] = f2bf(e[r][j]);
}

// ---------- kernel 2: out = x @ M via bf16 MFMA ----------
// Block: 512 threads = 8 waves; wave w owns output cols [32w, 32w+32).
// Block handles 64 rows (4 row-tiles of 16).  B (M) fragments resident in VGPRs.
// k-slot enumeration k = kt*32 + 8*(lane>>4) + i used consistently for A and B,
// so any hw k-permutation cancels.  C/D: col=lane&15, row=(lane>>4)*4+reg [m89].
__global__ __launch_bounds__(512, 4)
void clements_gemm(const float* __restrict__ x,
                   const unsigned short* __restrict__ mt,
                   float* __restrict__ out) {
    const int w   = threadIdx.x >> 6;   // 0..7
    const int t   = threadIdx.x & 63;
    const int l16 = t & 15;
    const int g   = t >> 4;             // 0..3
    const long rowbase = (long)blockIdx.x * 64;

    // Preload B fragments: Bf[kt][nt], col = 32w + nt*16 + l16, k = kt*32 + g*8 + i
    short8 Bf[8][2];
    #pragma unroll
    for (int nt = 0; nt < 2; ++nt) {
        const unsigned short* bp = mt + (32 * w + nt * 16 + l16) * 256 + g * 8;
        #pragma unroll
        for (int kt = 0; kt < 8; ++kt)
            Bf[kt][nt] = *(const short8*)(bp + kt * 32);
    }

    #pragma unroll 1
    for (int rt = 0; rt < 4; ++rt) {
        const float* xr = x + (rowbase + rt * 16 + l16) * 256 + g * 8;

        short8 Af[8];
        #pragma unroll
        for (int kt = 0; kt < 8; ++kt) {
            f32x4 v0 = *(const f32x4*)(xr + kt * 32);
            f32x4 v1 = *(const f32x4*)(xr + kt * 32 + 4);
            short8 a;
            a[0] = (short)f2bf(v0[0]); a[1] = (short)f2bf(v0[1]);
            a[2] = (short)f2bf(v0[2]); a[3] = (short)f2bf(v0[3]);
            a[4] = (short)f2bf(v1[0]); a[5] = (short)f2bf(v1[1]);
            a[6] = (short)f2bf(v1[2]); a[7] = (short)f2bf(v1[3]);
            Af[kt] = a;
        }

        f32x4 acc0 = {0.f, 0.f, 0.f, 0.f};
        f32x4 acc1 = {0.f, 0.f, 0.f, 0.f};
        #pragma unroll
        for (int kt = 0; kt < 8; ++kt) {
            acc0 = __builtin_amdgcn_mfma_f32_16x16x32_bf16(Af[kt], Bf[kt][0], acc0, 0, 0, 0);
            acc1 = __builtin_amdgcn_mfma_f32_16x16x32_bf16(Af[kt], Bf[kt][1], acc1, 0, 0, 0);
        }

        float* orow = out + (rowbase + rt * 16 + g * 4) * 256 + 32 * w + l16;
        #pragma unroll
        for (int j = 0; j < 4; ++j) {
            orow[(long)j * 256 +  0] = acc0[j];
            orow[(long)j * 256 + 16] = acc1[j];
        }
    }
}

// ---------- fallback: verified R1 direct kernel (used only if ws too small) ----------
__global__ __launch_bounds__(1024, 4)
void clements_direct(const float* __restrict__ x,
                     const float* __restrict__ theta,
                     float* __restrict__ out) {
    __shared__ float tbl[NLAYERS * DIM];
    const int tid = threadIdx.x;
    #pragma unroll
    for (int k = 0; k < 8; ++k) {
        int idx = tid + 1024 * k;
        int l = idx >> 7;
        int p = idx & 127;
        float s, c;
        sincosf(2.0f * theta[idx], &s, &c);
        if ((l & 1) && (p == 127)) { c = 1.0f; s = 0.0f; }
        tbl[idx * 2 + 0] = c;
        tbl[idx * 2 + 1] = s;
    }
    __syncthreads();

    const int w = tid >> 6;
    const int t = tid & 63;
    const long base = ((long)blockIdx.x * 16 + w) * 8;

    float e[8][4];
    #pragma unroll
    for (int r = 0; r < 8; ++r) {
        float4 v = ((const float4*)(x + (base + r) * (long)DIM))[t];
        e[r][0] = v.x; e[r][1] = v.y; e[r][2] = v.z; e[r][3] = v.w;
    }
    const float4* tbl4 = (const float4*)tbl;
    #pragma unroll 2
    for (int l = 0; l < NLAYERS; l += 2) {
        float4 cs = tbl4[(l << 6) + t];
        #pragma unroll
        for (int r = 0; r < 8; ++r) {
            float a0 = e[r][0], a1 = e[r][1], a2 = e[r][2], a3 = e[r][3];
            e[r][0] = cs.x * a0 + cs.y * a1;
            e[r][1] = cs.y * a0 - cs.x * a1;
            e[r][2] = cs.z * a2 + cs.w * a3;
            e[r][3] = cs.w * a2 - cs.z * a3;
        }
        float4 cs1 = tbl4[((l + 1) << 6) + t];
        #pragma unroll
        for (int r = 0; r < 8; ++r) {
            float a1 = e[r][1], a2 = e[r][2], a3 = e[r][3];
            float n1 = cs1.x * a1 + cs1.y * a2;
            float n2 = cs1.y * a1 - cs1.x * a2;
            float xjn = dpp_shl1_zero(e[r][0]);
            float n3  = cs1.z * a3 + cs1.w * xjn;
            float snd = cs1.w * a3 - cs1.z * xjn;
            e[r][0] = dpp_shr1_keep(e[r][0], snd);
            e[r][1] = n1; e[r][2] = n2; e[r][3] = n3;
        }
    }
    #pragma unroll
    for (int r = 0; r < 8; ++r) {
        float4 v;
        v.x = e[r][0]; v.y = e[r][1]; v.z = e[r][2]; v.w = e[r][3];
        ((float4*)(out + (base + r) * (long)DIM))[t] = v;
    }
}

extern "C" void kernel_launch(void* const* d_in, const int* in_sizes, int n_in,
                              void* d_out, int out_size, void* d_ws, size_t ws_size,
                              hipStream_t stream) {
    const float* x     = (const float*)d_in[0];
    const float* theta = (const float*)d_in[1];
    float* out = (float*)d_out;

    if (ws_size >= (size_t)(DIM * DIM * sizeof(unsigned short))) {
        unsigned short* mt = (unsigned short*)d_ws;
        hipLaunchKernelGGL(build_m_kernel, dim3(32), dim3(256), 0, stream, theta, mt);
        hipLaunchKernelGGL(clements_gemm, dim3(512), dim3(512), 0, stream, x, mt, out);
    } else {
        hipLaunchKernelGGL(clements_direct, dim3(256), dim3(1024), 0, stream, x, theta, out);
    }
}

// Round 3
// 31.882 us; speedup vs baseline: 1.8435x; 1.8435x over previous
//
#include <hip/hip_runtime.h>
#include <math.h>

#define DIM 256
#define NLAYERS 64

typedef __attribute__((ext_vector_type(8))) short short8;
typedef __attribute__((ext_vector_type(4))) float f32x4;

// ---------- helpers ----------
__device__ __forceinline__ float dpp_shl1_zero(float v) {
    int r = __builtin_amdgcn_update_dpp(0, __float_as_int(v), 0x130, 0xF, 0xF, true);
    return __int_as_float(r);
}
__device__ __forceinline__ float dpp_shr1_keep(float oldv, float v) {
    int r = __builtin_amdgcn_update_dpp(__float_as_int(oldv), __float_as_int(v), 0x138, 0xF, 0xF, false);
    return __int_as_float(r);
}
// f32 -> bf16 bits, RNE.
__device__ __forceinline__ unsigned short f2bf(float f) {
    unsigned u = __float_as_uint(f);
    u += 0x7FFFu + ((u >> 16) & 1u);
    return (unsigned short)(u >> 16);
}

// ---------- kernel 1: trig table (one sincos per thread) ----------
// tbl[idx] = {cos,sin}(2*theta[idx]), idx = l*128 + p; identity for odd-layer pair 127.
__global__ __launch_bounds__(256)
void trig_kernel(const float* __restrict__ theta, float* __restrict__ tbl) {
    int idx = blockIdx.x * 256 + threadIdx.x;   // 0..8191
    int l = idx >> 7, p = idx & 127;
    float s, c;
    sincosf(2.0f * theta[idx], &s, &c);
    if ((l & 1) && (p == 127)) { c = 1.0f; s = 0.0f; }
    float2 cs; cs.x = c; cs.y = s;
    ((float2*)tbl)[idx] = cs;
}

// ---------- kernel 2: build M^T (bf16) ----------
// 64 blocks x 256 threads; 4 waves x 1 identity row each -> 4 rows of M per block.
__global__ __launch_bounds__(256)
void build_m_kernel(const float* __restrict__ gtbl, unsigned short* __restrict__ mt) {
    __shared__ float tbl[NLAYERS * DIM];   // 64 KB
    const int tid = threadIdx.x;
    #pragma unroll
    for (int k = 0; k < 16; ++k)
        ((f32x4*)tbl)[tid + 256 * k] = ((const f32x4*)gtbl)[tid + 256 * k];
    __syncthreads();

    const int w = tid >> 6;
    const int t = tid & 63;
    const int row = blockIdx.x * 4 + w;    // 0..255

    float e[4];
    #pragma unroll
    for (int j = 0; j < 4; ++j) e[j] = (4 * t + j == row) ? 1.0f : 0.0f;

    const float4* tbl4 = (const float4*)tbl;
    #pragma unroll 2
    for (int l = 0; l < NLAYERS; l += 2) {
        float4 cs = tbl4[(l << 6) + t];
        {
            float a0 = e[0], a1 = e[1], a2 = e[2], a3 = e[3];
            e[0] = cs.x * a0 + cs.y * a1;
            e[1] = cs.y * a0 - cs.x * a1;
            e[2] = cs.z * a2 + cs.w * a3;
            e[3] = cs.w * a2 - cs.z * a3;
        }
        float4 cs1 = tbl4[((l + 1) << 6) + t];
        {
            float a1 = e[1], a2 = e[2], a3 = e[3];
            float n1 = cs1.x * a1 + cs1.y * a2;
            float n2 = cs1.y * a1 - cs1.x * a2;
            float xjn = dpp_shl1_zero(e[0]);
            float n3  = cs1.z * a3 + cs1.w * xjn;
            float snd = cs1.w * a3 - cs1.z * xjn;
            e[0] = dpp_shr1_keep(e[0], snd);
            e[1] = n1; e[2] = n2; e[3] = n3;
        }
    }

    // M[row][4t+j] -> mt[(4t+j)*256 + row]
    #pragma unroll
    for (int j = 0; j < 4; ++j)
        mt[(4 * t + j) * 256 + row] = f2bf(e[j]);
}

// ---------- kernel 3: out = x @ M via bf16 MFMA, LDS fragment staging ----------
// Block: 512 threads = 8 waves; wave w owns output cols [32w, 32w+32).
// 64 rows/block as two 32-row chunks, double-buffered in LDS in *fragment order*:
// afrag[ch][ ((rtl*8 + kt)*64 + t)*8 + i ] = bf16 x[row = ch*32+rtl*16+(t&15)]
//                                              [k = kt*32 + (t>>4)*8 + i]
// so every wave's A-fragment load is a contiguous, conflict-free ds_read_b128.
// k-slot enumeration k = kt*32 + 8*(t>>4) + i used identically for A and B.
// C/D: col=lane&15, row=(lane>>4)*4+reg [m89].
__global__ __launch_bounds__(512, 4)
void clements_gemm(const float* __restrict__ x,
                   const unsigned short* __restrict__ mt,
                   float* __restrict__ out) {
    __shared__ unsigned short afrag[2][8192];   // 2 x 16 KB

    const int tid = threadIdx.x;
    const int w   = tid >> 6;       // wave 0..7
    const int t   = tid & 63;
    const int l16 = t & 15;
    const int g   = t >> 4;         // 0..3
    const long rowbase = (long)blockIdx.x * 64;

    // --- B preload: Bf[kt][nt], col = 32w + nt*16 + l16, k = kt*32 + g*8 + i
    short8 Bf[8][2];
    #pragma unroll
    for (int nt = 0; nt < 2; ++nt) {
        const unsigned short* bp = mt + (32 * w + nt * 16 + l16) * 256 + g * 8;
        #pragma unroll
        for (int kt = 0; kt < 8; ++kt)
            Bf[kt][nt] = *(const short8*)(bp + kt * 32);
    }

    // --- staging thread mapping: thread -> (row-in-chunk, 16-f32 segment)
    const int sr   = tid >> 4;        // 0..31
    const int seg  = tid & 15;        // segment of 16 f32 = 64 B
    const int skt  = seg >> 1;
    const int sg0  = (seg & 1) * 2;
    const int srtl = sr >> 4;
    const int sl16 = sr & 15;
    const int slot0 = ((srtl * 8 + skt) * 64 + (sg0 * 16 + sl16)) * 8;
    const int slot1 = ((srtl * 8 + skt) * 64 + ((sg0 + 1) * 16 + sl16)) * 8;
    const float* xp = x + (rowbase + sr) * 256 + seg * 16;

    // --- load + stage chunk 0
    {
        f32x4 v0 = *(const f32x4*)(xp + 0);
        f32x4 v1 = *(const f32x4*)(xp + 4);
        f32x4 v2 = *(const f32x4*)(xp + 8);
        f32x4 v3 = *(const f32x4*)(xp + 12);
        short8 h0, h1;
        h0[0]=f2bf(v0[0]); h0[1]=f2bf(v0[1]); h0[2]=f2bf(v0[2]); h0[3]=f2bf(v0[3]);
        h0[4]=f2bf(v1[0]); h0[5]=f2bf(v1[1]); h0[6]=f2bf(v1[2]); h0[7]=f2bf(v1[3]);
        h1[0]=f2bf(v2[0]); h1[1]=f2bf(v2[1]); h1[2]=f2bf(v2[2]); h1[3]=f2bf(v2[3]);
        h1[4]=f2bf(v3[0]); h1[5]=f2bf(v3[1]); h1[6]=f2bf(v3[2]); h1[7]=f2bf(v3[3]);
        *(short8*)&afrag[0][slot0] = h0;
        *(short8*)&afrag[0][slot1] = h1;
    }
    __syncthreads();

    // --- issue chunk-1 global loads early (hide under chunk-0 compute)
    f32x4 u0 = *(const f32x4*)(xp + 32 * 256 + 0);
    f32x4 u1 = *(const f32x4*)(xp + 32 * 256 + 4);
    f32x4 u2 = *(const f32x4*)(xp + 32 * 256 + 8);
    f32x4 u3 = *(const f32x4*)(xp + 32 * 256 + 12);

    // --- compute chunk 0 (rt 0,1)
    #pragma unroll
    for (int rtl = 0; rtl < 2; ++rtl) {
        short8 Af[8];
        #pragma unroll
        for (int kt = 0; kt < 8; ++kt)
            Af[kt] = *(const short8*)&afrag[0][((rtl * 8 + kt) * 64 + t) * 8];
        f32x4 acc0 = {0.f,0.f,0.f,0.f}, acc1 = {0.f,0.f,0.f,0.f};
        #pragma unroll
        for (int kt = 0; kt < 8; ++kt) {
            acc0 = __builtin_amdgcn_mfma_f32_16x16x32_bf16(Af[kt], Bf[kt][0], acc0, 0, 0, 0);
            acc1 = __builtin_amdgcn_mfma_f32_16x16x32_bf16(Af[kt], Bf[kt][1], acc1, 0, 0, 0);
        }
        float* orow = out + (rowbase + rtl * 16 + g * 4) * 256 + 32 * w + l16;
        #pragma unroll
        for (int j = 0; j < 4; ++j) {
            orow[(long)j * 256 +  0] = acc0[j];
            orow[(long)j * 256 + 16] = acc1[j];
        }
    }

    // --- stage chunk 1
    {
        short8 h0, h1;
        h0[0]=f2bf(u0[0]); h0[1]=f2bf(u0[1]); h0[2]=f2bf(u0[2]); h0[3]=f2bf(u0[3]);
        h0[4]=f2bf(u1[0]); h0[5]=f2bf(u1[1]); h0[6]=f2bf(u1[2]); h0[7]=f2bf(u1[3]);
        h1[0]=f2bf(u2[0]); h1[1]=f2bf(u2[1]); h1[2]=f2bf(u2[2]); h1[3]=f2bf(u2[3]);
        h1[4]=f2bf(u3[0]); h1[5]=f2bf(u3[1]); h1[6]=f2bf(u3[2]); h1[7]=f2bf(u3[3]);
        *(short8*)&afrag[1][slot0] = h0;
        *(short8*)&afrag[1][slot1] = h1;
    }
    __syncthreads();

    // --- compute chunk 1 (rt 2,3)
    #pragma unroll
    for (int rtl = 0; rtl < 2; ++rtl) {
        short8 Af[8];
        #pragma unroll
        for (int kt = 0; kt < 8; ++kt)
            Af[kt] = *(const short8*)&afrag[1][((rtl * 8 + kt) * 64 + t) * 8];
        f32x4 acc0 = {0.f,0.f,0.f,0.f}, acc1 = {0.f,0.f,0.f,0.f};
        #pragma unroll
        for (int kt = 0; kt < 8; ++kt) {
            acc0 = __builtin_amdgcn_mfma_f32_16x16x32_bf16(Af[kt], Bf[kt][0], acc0, 0, 0, 0);
            acc1 = __builtin_amdgcn_mfma_f32_16x16x32_bf16(Af[kt], Bf[kt][1], acc1, 0, 0, 0);
        }
        float* orow = out + (rowbase + 32 + rtl * 16 + g * 4) * 256 + 32 * w + l16;
        #pragma unroll
        for (int j = 0; j < 4; ++j) {
            orow[(long)j * 256 +  0] = acc0[j];
            orow[(long)j * 256 + 16] = acc1[j];
        }
    }
}

// ---------- fallback: verified R1 direct kernel ----------
__global__ __launch_bounds__(1024, 4)
void clements_direct(const float* __restrict__ x,
                     const float* __restrict__ theta,
                     float* __restrict__ out) {
    __shared__ float tbl[NLAYERS * DIM];
    const int tid = threadIdx.x;
    #pragma unroll
    for (int k = 0; k < 8; ++k) {
        int idx = tid + 1024 * k;
        int l = idx >> 7;
        int p = idx & 127;
        float s, c;
        sincosf(2.0f * theta[idx], &s, &c);
        if ((l & 1) && (p == 127)) { c = 1.0f; s = 0.0f; }
        tbl[idx * 2 + 0] = c;
        tbl[idx * 2 + 1] = s;
    }
    __syncthreads();
    const int w = tid >> 6;
    const int t = tid & 63;
    const long base = ((long)blockIdx.x * 16 + w) * 8;
    float e[8][4];
    #pragma unroll
    for (int r = 0; r < 8; ++r) {
        float4 v = ((const float4*)(x + (base + r) * (long)DIM))[t];
        e[r][0] = v.x; e[r][1] = v.y; e[r][2] = v.z; e[r][3] = v.w;
    }
    const float4* tbl4 = (const float4*)tbl;
    #pragma unroll 2
    for (int l = 0; l < NLAYERS; l += 2) {
        float4 cs = tbl4[(l << 6) + t];
        #pragma unroll
        for (int r = 0; r < 8; ++r) {
            float a0 = e[r][0], a1 = e[r][1], a2 = e[r][2], a3 = e[r][3];
            e[r][0] = cs.x * a0 + cs.y * a1;
            e[r][1] = cs.y * a0 - cs.x * a1;
            e[r][2] = cs.z * a2 + cs.w * a3;
            e[r][3] = cs.w * a2 - cs.z * a3;
        }
        float4 cs1 = tbl4[((l + 1) << 6) + t];
        #pragma unroll
        for (int r = 0; r < 8; ++r) {
            float a1 = e[r][1], a2 = e[r][2], a3 = e[r][3];
            float n1 = cs1.x * a1 + cs1.y * a2;
            float n2 = cs1.y * a1 - cs1.x * a2;
            float xjn = dpp_shl1_zero(e[r][0]);
            float n3  = cs1.z * a3 + cs1.w * xjn;
            float snd = cs1.w * a3 - cs1.z * xjn;
            e[r][0] = dpp_shr1_keep(e[r][0], snd);
            e[r][1] = n1; e[r][2] = n2; e[r][3] = n3;
        }
    }
    #pragma unroll
    for (int r = 0; r < 8; ++r) {
        float4 v;
        v.x = e[r][0]; v.y = e[r][1]; v.z = e[r][2]; v.w = e[r][3];
        ((float4*)(out + (base + r) * (long)DIM))[t] = v;
    }
}

extern "C" void kernel_launch(void* const* d_in, const int* in_sizes, int n_in,
                              void* d_out, int out_size, void* d_ws, size_t ws_size,
                              hipStream_t stream) {
    const float* x     = (const float*)d_in[0];
    const float* theta = (const float*)d_in[1];
    float* out = (float*)d_out;

    const size_t need = 64 * 1024 + DIM * DIM * sizeof(unsigned short);  // tbl + mt
    if (ws_size >= need) {
        float* tbl = (float*)d_ws;
        unsigned short* mt = (unsigned short*)((char*)d_ws + 64 * 1024);
        hipLaunchKernelGGL(trig_kernel,    dim3(32),  dim3(256), 0, stream, theta, tbl);
        hipLaunchKernelGGL(build_m_kernel, dim3(64),  dim3(256), 0, stream, tbl, mt);
        hipLaunchKernelGGL(clements_gemm,  dim3(512), dim3(512), 0, stream, x, mt, out);
    } else {
        hipLaunchKernelGGL(clements_direct, dim3(256), dim3(1024), 0, stream, x, theta, out);
    }
}

// Round 4
// 31.312 us; speedup vs baseline: 1.8770x; 1.0182x over previous
//
#include <hip/hip_runtime.h>
#include <math.h>

#define DIM 256
#define NLAYERS 64

typedef __attribute__((ext_vector_type(8))) short short8;
typedef __attribute__((ext_vector_type(4))) float f32x4;

// ---------- helpers ----------
__device__ __forceinline__ float dpp_shl1_zero(float v) {
    int r = __builtin_amdgcn_update_dpp(0, __float_as_int(v), 0x130, 0xF, 0xF, true);
    return __int_as_float(r);
}
__device__ __forceinline__ float dpp_shr1_keep(float oldv, float v) {
    int r = __builtin_amdgcn_update_dpp(__float_as_int(oldv), __float_as_int(v), 0x138, 0xF, 0xF, false);
    return __int_as_float(r);
}
// f32 -> bf16 bits, RNE.
__device__ __forceinline__ unsigned short f2bf(float f) {
    unsigned u = __float_as_uint(f);
    u += 0x7FFFu + ((u >> 16) & 1u);
    return (unsigned short)(u >> 16);
}

// ---------- kernel 1: build M in MFMA-fragment order (bf16) ----------
// 64 blocks x 256 threads. Each block rebuilds the trig table in LDS (32
// pipelined sincosf/thread, ~0.8us, runs on 64 CUs in parallel), then its 4
// waves each push one identity row through the 64 layers. Row `row` of M is
// B[k=row][col]; stored at fragment slot:
//   bfrag[(((col>>4)*8 + (k>>5))*64 + ((k>>3)&3)*16 + (col&15))*8 + (k&7)]
// which is exactly the order clements_gemm's waves read with consecutive-lane
// 16B loads.
__global__ __launch_bounds__(256)
void build_m_kernel(const float* __restrict__ theta, unsigned short* __restrict__ bfrag) {
    __shared__ float tbl[NLAYERS * DIM];   // 64 KB: [(l*128+p)*2 + {c,s}]
    const int tid = threadIdx.x;
    #pragma unroll 4
    for (int kk = 0; kk < 32; ++kk) {
        int idx = tid + 256 * kk;          // idx = l*128 + p
        int l = idx >> 7, p = idx & 127;
        float s, c;
        sincosf(2.0f * theta[idx], &s, &c);
        if ((l & 1) && (p == 127)) { c = 1.0f; s = 0.0f; }   // odd-layer passthrough pair
        tbl[idx * 2 + 0] = c;
        tbl[idx * 2 + 1] = s;
    }
    __syncthreads();

    const int w = tid >> 6;
    const int t = tid & 63;
    const int row = blockIdx.x * 4 + w;    // 0..255 — this wave builds M row `row`

    float e[4];
    #pragma unroll
    for (int j = 0; j < 4; ++j) e[j] = (4 * t + j == row) ? 1.0f : 0.0f;

    const float4* tbl4 = (const float4*)tbl;
    #pragma unroll 2
    for (int l = 0; l < NLAYERS; l += 2) {
        float4 cs = tbl4[(l << 6) + t];
        {
            float a0 = e[0], a1 = e[1], a2 = e[2], a3 = e[3];
            e[0] = cs.x * a0 + cs.y * a1;
            e[1] = cs.y * a0 - cs.x * a1;
            e[2] = cs.z * a2 + cs.w * a3;
            e[3] = cs.w * a2 - cs.z * a3;
        }
        float4 cs1 = tbl4[((l + 1) << 6) + t];
        {
            float a1 = e[1], a2 = e[2], a3 = e[3];
            float n1 = cs1.x * a1 + cs1.y * a2;
            float n2 = cs1.y * a1 - cs1.x * a2;
            float xjn = dpp_shl1_zero(e[0]);
            float n3  = cs1.z * a3 + cs1.w * xjn;
            float snd = cs1.w * a3 - cs1.z * xjn;
            e[0] = dpp_shr1_keep(e[0], snd);
            e[1] = n1; e[2] = n2; e[3] = n3;
        }
    }

    const int kt = row >> 5, g8 = (row >> 3) & 3, ki = row & 7;
    #pragma unroll
    for (int j = 0; j < 4; ++j) {
        int col = 4 * t + j;
        bfrag[(((col >> 4) * 8 + kt) * 64 + g8 * 16 + (col & 15)) * 8 + ki] = f2bf(e[j]);
    }
}

// ---------- kernel 2: out = x @ M via bf16 MFMA, LDS fragment staging ----------
// Block: 512 threads = 8 waves; wave w owns output cols [32w, 32w+32).
// 64 rows/block as two 32-row chunks, double-buffered in LDS in fragment order:
// afrag[ch][((rtl*8+kt)*64 + t)*8 + i] = bf16 x[row=ch*32+rtl*16+(t&15)][k=kt*32+(t>>4)*8+i]
// B fragments read fully coalesced from bfrag (consecutive lanes -> consecutive 16B).
// k-slot enumeration k = kt*32 + 8*(t>>4) + i identical for A and B (hw perm cancels).
// C/D: col=lane&15, row=(lane>>4)*4+reg [m89].
__global__ __launch_bounds__(512, 4)
void clements_gemm(const float* __restrict__ x,
                   const unsigned short* __restrict__ bfrag,
                   float* __restrict__ out) {
    __shared__ unsigned short afrag[2][8192];   // 2 x 16 KB

    const int tid = threadIdx.x;
    const int w   = tid >> 6;       // wave 0..7
    const int t   = tid & 63;
    const int l16 = t & 15;
    const int g   = t >> 4;         // 0..3
    const long rowbase = (long)blockIdx.x * 64;

    // staging thread mapping: thread -> (row-in-chunk, 16-f32 segment)
    const int sr   = tid >> 4;        // 0..31
    const int seg  = tid & 15;        // 64B segment
    const int skt  = seg >> 1;
    const int sg0  = (seg & 1) * 2;
    const int srtl = sr >> 4;
    const int sl16 = sr & 15;
    const int slot0 = ((srtl * 8 + skt) * 64 + (sg0 * 16 + sl16)) * 8;
    const int slot1 = ((srtl * 8 + skt) * 64 + ((sg0 + 1) * 16 + sl16)) * 8;
    const float* xp = x + (rowbase + sr) * 256 + seg * 16;

    // --- issue chunk-0 x loads first (HBM, longest latency)
    f32x4 v0 = *(const f32x4*)(xp + 0);
    f32x4 v1 = *(const f32x4*)(xp + 4);
    f32x4 v2 = *(const f32x4*)(xp + 8);
    f32x4 v3 = *(const f32x4*)(xp + 12);

    // --- B preload (coalesced): Bf[kt][nt] from fragment-ordered bfrag
    short8 Bf[8][2];
    {
        const short8* bp = (const short8*)bfrag;
        #pragma unroll
        for (int nt = 0; nt < 2; ++nt)
            #pragma unroll
            for (int kt = 0; kt < 8; ++kt)
                Bf[kt][nt] = bp[((w * 2 + nt) * 8 + kt) * 64 + t];
    }

    // --- stage chunk 0
    {
        short8 h0, h1;
        h0[0]=f2bf(v0[0]); h0[1]=f2bf(v0[1]); h0[2]=f2bf(v0[2]); h0[3]=f2bf(v0[3]);
        h0[4]=f2bf(v1[0]); h0[5]=f2bf(v1[1]); h0[6]=f2bf(v1[2]); h0[7]=f2bf(v1[3]);
        h1[0]=f2bf(v2[0]); h1[1]=f2bf(v2[1]); h1[2]=f2bf(v2[2]); h1[3]=f2bf(v2[3]);
        h1[4]=f2bf(v3[0]); h1[5]=f2bf(v3[1]); h1[6]=f2bf(v3[2]); h1[7]=f2bf(v3[3]);
        *(short8*)&afrag[0][slot0] = h0;
        *(short8*)&afrag[0][slot1] = h1;
    }
    __syncthreads();

    // --- issue chunk-1 x loads early (hide under chunk-0 compute)
    f32x4 u0 = *(const f32x4*)(xp + 32 * 256 + 0);
    f32x4 u1 = *(const f32x4*)(xp + 32 * 256 + 4);
    f32x4 u2 = *(const f32x4*)(xp + 32 * 256 + 8);
    f32x4 u3 = *(const f32x4*)(xp + 32 * 256 + 12);

    // --- compute chunk 0 (rt 0,1)
    #pragma unroll
    for (int rtl = 0; rtl < 2; ++rtl) {
        short8 Af[8];
        #pragma unroll
        for (int kt = 0; kt < 8; ++kt)
            Af[kt] = *(const short8*)&afrag[0][((rtl * 8 + kt) * 64 + t) * 8];
        f32x4 acc0 = {0.f,0.f,0.f,0.f}, acc1 = {0.f,0.f,0.f,0.f};
        #pragma unroll
        for (int kt = 0; kt < 8; ++kt) {
            acc0 = __builtin_amdgcn_mfma_f32_16x16x32_bf16(Af[kt], Bf[kt][0], acc0, 0, 0, 0);
            acc1 = __builtin_amdgcn_mfma_f32_16x16x32_bf16(Af[kt], Bf[kt][1], acc1, 0, 0, 0);
        }
        float* orow = out + (rowbase + rtl * 16 + g * 4) * 256 + 32 * w + l16;
        #pragma unroll
        for (int j = 0; j < 4; ++j) {
            orow[(long)j * 256 +  0] = acc0[j];
            orow[(long)j * 256 + 16] = acc1[j];
        }
    }

    // --- stage chunk 1
    {
        short8 h0, h1;
        h0[0]=f2bf(u0[0]); h0[1]=f2bf(u0[1]); h0[2]=f2bf(u0[2]); h0[3]=f2bf(u0[3]);
        h0[4]=f2bf(u1[0]); h0[5]=f2bf(u1[1]); h0[6]=f2bf(u1[2]); h0[7]=f2bf(u1[3]);
        h1[0]=f2bf(u2[0]); h1[1]=f2bf(u2[1]); h1[2]=f2bf(u2[2]); h1[3]=f2bf(u2[3]);
        h1[4]=f2bf(u3[0]); h1[5]=f2bf(u3[1]); h1[6]=f2bf(u3[2]); h1[7]=f2bf(u3[3]);
        *(short8*)&afrag[1][slot0] = h0;
        *(short8*)&afrag[1][slot1] = h1;
    }
    __syncthreads();

    // --- compute chunk 1 (rt 2,3)
    #pragma unroll
    for (int rtl = 0; rtl < 2; ++rtl) {
        short8 Af[8];
        #pragma unroll
        for (int kt = 0; kt < 8; ++kt)
            Af[kt] = *(const short8*)&afrag[1][((rtl * 8 + kt) * 64 + t) * 8];
        f32x4 acc0 = {0.f,0.f,0.f,0.f}, acc1 = {0.f,0.f,0.f,0.f};
        #pragma unroll
        for (int kt = 0; kt < 8; ++kt) {
            acc0 = __builtin_amdgcn_mfma_f32_16x16x32_bf16(Af[kt], Bf[kt][0], acc0, 0, 0, 0);
            acc1 = __builtin_amdgcn_mfma_f32_16x16x32_bf16(Af[kt], Bf[kt][1], acc1, 0, 0, 0);
        }
        float* orow = out + (rowbase + 32 + rtl * 16 + g * 4) * 256 + 32 * w + l16;
        #pragma unroll
        for (int j = 0; j < 4; ++j) {
            orow[(long)j * 256 +  0] = acc0[j];
            orow[(long)j * 256 + 16] = acc1[j];
        }
    }
}

// ---------- fallback: verified R1 direct kernel (ws too small) ----------
__global__ __launch_bounds__(1024, 4)
void clements_direct(const float* __restrict__ x,
                     const float* __restrict__ theta,
                     float* __restrict__ out) {
    __shared__ float tbl[NLAYERS * DIM];
    const int tid = threadIdx.x;
    #pragma unroll
    for (int k = 0; k < 8; ++k) {
        int idx = tid + 1024 * k;
        int l = idx >> 7;
        int p = idx & 127;
        float s, c;
        sincosf(2.0f * theta[idx], &s, &c);
        if ((l & 1) && (p == 127)) { c = 1.0f; s = 0.0f; }
        tbl[idx * 2 + 0] = c;
        tbl[idx * 2 + 1] = s;
    }
    __syncthreads();
    const int w = tid >> 6;
    const int t = tid & 63;
    const long base = ((long)blockIdx.x * 16 + w) * 8;
    float e[8][4];
    #pragma unroll
    for (int r = 0; r < 8; ++r) {
        float4 v = ((const float4*)(x + (base + r) * (long)DIM))[t];
        e[r][0] = v.x; e[r][1] = v.y; e[r][2] = v.z; e[r][3] = v.w;
    }
    const float4* tbl4 = (const float4*)tbl;
    #pragma unroll 2
    for (int l = 0; l < NLAYERS; l += 2) {
        float4 cs = tbl4[(l << 6) + t];
        #pragma unroll
        for (int r = 0; r < 8; ++r) {
            float a0 = e[r][0], a1 = e[r][1], a2 = e[r][2], a3 = e[r][3];
            e[r][0] = cs.x * a0 + cs.y * a1;
            e[r][1] = cs.y * a0 - cs.x * a1;
            e[r][2] = cs.z * a2 + cs.w * a3;
            e[r][3] = cs.w * a2 - cs.z * a3;
        }
        float4 cs1 = tbl4[((l + 1) << 6) + t];
        #pragma unroll
        for (int r = 0; r < 8; ++r) {
            float a1 = e[r][1], a2 = e[r][2], a3 = e[r][3];
            float n1 = cs1.x * a1 + cs1.y * a2;
            float n2 = cs1.y * a1 - cs1.x * a2;
            float xjn = dpp_shl1_zero(e[r][0]);
            float n3  = cs1.z * a3 + cs1.w * xjn;
            float snd = cs1.w * a3 - cs1.z * xjn;
            e[r][0] = dpp_shr1_keep(e[r][0], snd);
            e[r][1] = n1; e[r][2] = n2; e[r][3] = n3;
        }
    }
    #pragma unroll
    for (int r = 0; r < 8; ++r) {
        float4 v;
        v.x = e[r][0]; v.y = e[r][1]; v.z = e[r][2]; v.w = e[r][3];
        ((float4*)(out + (base + r) * (long)DIM))[t] = v;
    }
}

extern "C" void kernel_launch(void* const* d_in, const int* in_sizes, int n_in,
                              void* d_out, int out_size, void* d_ws, size_t ws_size,
                              hipStream_t stream) {
    const float* x     = (const float*)d_in[0];
    const float* theta = (const float*)d_in[1];
    float* out = (float*)d_out;

    const size_t need = (size_t)DIM * DIM * sizeof(unsigned short);  // bfrag, 128 KB
    if (ws_size >= need) {
        unsigned short* bfrag = (unsigned short*)d_ws;
        hipLaunchKernelGGL(build_m_kernel, dim3(64),  dim3(256), 0, stream, theta, bfrag);
        hipLaunchKernelGGL(clements_gemm,  dim3(512), dim3(512), 0, stream, x, bfrag, out);
    } else {
        hipLaunchKernelGGL(clements_direct, dim3(256), dim3(1024), 0, stream, x, theta, out);
    }
}

// Round 6
// 26.739 us; speedup vs baseline: 2.1981x; 1.1710x over previous
//
#include <hip/hip_runtime.h>
#include <math.h>

#define DIM 256
#define NLAYERS 64

typedef __attribute__((ext_vector_type(8))) short short8;
typedef __attribute__((ext_vector_type(4))) float f32x4;

// ---------- helpers ----------
__device__ __forceinline__ float dpp_shl1_zero(float v) {
    int r = __builtin_amdgcn_update_dpp(0, __float_as_int(v), 0x130, 0xF, 0xF, true);
    return __int_as_float(r);
}
__device__ __forceinline__ float dpp_shr1_keep(float oldv, float v) {
    int r = __builtin_amdgcn_update_dpp(__float_as_int(oldv), __float_as_int(v), 0x138, 0xF, 0xF, false);
    return __int_as_float(r);
}
// f32 -> bf16 bits, RNE.
__device__ __forceinline__ unsigned short f2bf(float f) {
    unsigned u = __float_as_uint(f);
    u += 0x7FFFu + ((u >> 16) & 1u);
    return (unsigned short)(u >> 16);
}

// ---------- kernel 1: build M in MFMA-fragment order (bf16) ----------
// 16 blocks x 1024 threads (16 waves = 4/SIMD to hide table-read latency).
// Row k of M stored at fragment granule:
//   bfrag[(((col>>4)*8 + (k>>5))*64 + ((k>>3)&3)*16 + (col&15))*8 + (k&7)]
__global__ __launch_bounds__(1024)
void build_m_kernel(const float* __restrict__ theta, unsigned short* __restrict__ bfrag) {
    __shared__ float tbl[NLAYERS * DIM];   // 64 KB: [(l*128+p)*2 + {c,s}]
    const int tid = threadIdx.x;
    #pragma unroll
    for (int kk = 0; kk < 8; ++kk) {
        int idx = tid + 1024 * kk;         // idx = l*128 + p
        int l = idx >> 7, p = idx & 127;
        float s, c;
        sincosf(2.0f * theta[idx], &s, &c);
        if ((l & 1) && (p == 127)) { c = 1.0f; s = 0.0f; }   // odd-layer passthrough pair
        tbl[idx * 2 + 0] = c;
        tbl[idx * 2 + 1] = s;
    }
    __syncthreads();

    const int w = tid >> 6;
    const int t = tid & 63;
    const int row = blockIdx.x * 16 + w;   // 0..255 — this wave builds M row `row`

    float e[4];
    #pragma unroll
    for (int j = 0; j < 4; ++j) e[j] = (4 * t + j == row) ? 1.0f : 0.0f;

    const float4* tbl4 = (const float4*)tbl;
    #pragma unroll 2
    for (int l = 0; l < NLAYERS; l += 2) {
        float4 cs = tbl4[(l << 6) + t];
        {
            float a0 = e[0], a1 = e[1], a2 = e[2], a3 = e[3];
            e[0] = cs.x * a0 + cs.y * a1;
            e[1] = cs.y * a0 - cs.x * a1;
            e[2] = cs.z * a2 + cs.w * a3;
            e[3] = cs.w * a2 - cs.z * a3;
        }
        float4 cs1 = tbl4[((l + 1) << 6) + t];
        {
            float a1 = e[1], a2 = e[2], a3 = e[3];
            float n1 = cs1.x * a1 + cs1.y * a2;
            float n2 = cs1.y * a1 - cs1.x * a2;
            float xjn = dpp_shl1_zero(e[0]);
            float n3  = cs1.z * a3 + cs1.w * xjn;
            float snd = cs1.w * a3 - cs1.z * xjn;
            e[0] = dpp_shr1_keep(e[0], snd);
            e[1] = n1; e[2] = n2; e[3] = n3;
        }
    }

    const int kt = row >> 5, g8 = (row >> 3) & 3, ki = row & 7;
    #pragma unroll
    for (int j = 0; j < 4; ++j) {
        int col = 4 * t + j;
        bfrag[(((col >> 4) * 8 + kt) * 64 + g8 * 16 + (col & 15)) * 8 + ki] = f2bf(e[j]);
    }
}

// ---------- kernel 2: out = x @ M via bf16 MFMA, 4-stage prefetch pipeline ----
// Block: 512 threads = 8 waves; wave w owns output cols [32w, 32w+32).
// B per-wave in registers (16 short8 = 64 VGPR), loaded coalesced from
// fragment-ordered bfrag (consecutive lanes -> consecutive 16B).
// A: 64 rows/block in 4 chunks of 16 rows; LDS ping-pong 2x8KB; pipeline:
//   iter i: issue loads(i+2) | compute(i) from afrag[i&1] | cvt+write(i+1) | bar
// so >=2 chunks of HBM loads stay in flight the whole block (no bubbles).
// A-granule (q=kt, s=g*16+l16) stored at q*64 + (s^q) (XOR bank swizzle):
//   writer bank-group (sr&7)^q uniform, reader (t&7)^kt uniform — conflict-free.
// k enumeration k = kt*32 + 8*(t>>4) + i identical for A and B (hw perm cancels).
// C/D: col=lane&15, row=(lane>>4)*4+reg [m89].
__global__ __launch_bounds__(512, 4)
void clements_gemm(const float* __restrict__ x,
                   const unsigned short* __restrict__ bfrag,
                   float* __restrict__ out) {
    __shared__ unsigned short afrag[2][4096];   // 2 x 8 KB

    const int tid = threadIdx.x;
    const int w   = tid >> 6;       // wave 0..7
    const int t   = tid & 63;
    const int l16 = t & 15;
    const int g   = t >> 4;         // 0..3
    const long rowbase = (long)blockIdx.x * 64;

    // staging map: thread -> (row sr in 16-row chunk, 8-f32 segment seg)
    const int sr  = tid >> 5;       // 0..15
    const int seg = tid & 31;       // 0..31 (cols seg*8 .. seg*8+7)
    const int q   = seg >> 2;       // kt of this segment
    const int sg  = seg & 3;        // k-octet g of this segment
    const int wslot = (q * 64 + ((sg * 16 + sr) ^ q)) * 8;   // swizzled granule
    const float* xp = x + (rowbase + sr) * 256 + seg * 8;

    f32x4 pref[4][2];
#define LOADC(i) { pref[i][0] = *(const f32x4*)(xp + (i) * 16 * 256);      \
                   pref[i][1] = *(const f32x4*)(xp + (i) * 16 * 256 + 4); }
#define WRITEC(i) { short8 h;                                              \
        h[0]=f2bf(pref[i][0][0]); h[1]=f2bf(pref[i][0][1]);                \
        h[2]=f2bf(pref[i][0][2]); h[3]=f2bf(pref[i][0][3]);                \
        h[4]=f2bf(pref[i][1][0]); h[5]=f2bf(pref[i][1][1]);                \
        h[6]=f2bf(pref[i][1][2]); h[7]=f2bf(pref[i][1][3]);                \
        *(short8*)&afrag[(i) & 1][wslot] = h; }

    // --- prologue: chunk-0 + chunk-1 HBM loads in flight, then B preload
    LOADC(0)
    LOADC(1)

    short8 Bf[8][2];
    {
        const short8* bp = (const short8*)bfrag;
        #pragma unroll
        for (int nt = 0; nt < 2; ++nt)
            #pragma unroll
            for (int kt = 0; kt < 8; ++kt)
                Bf[kt][nt] = bp[((w * 2 + nt) * 8 + kt) * 64 + t];
    }

    WRITEC(0)
    __syncthreads();

    // --- main pipeline
    #pragma unroll
    for (int i = 0; i < 4; ++i) {
        if (i + 2 < 4) LOADC(i + 2)

        f32x4 a0 = {0.f,0.f,0.f,0.f}, a1 = {0.f,0.f,0.f,0.f};
        #pragma unroll
        for (int kt = 0; kt < 8; ++kt) {
            short8 A = *(const short8*)&afrag[i & 1][(kt * 64 + (t ^ kt)) * 8];
            a0 = __builtin_amdgcn_mfma_f32_16x16x32_bf16(A, Bf[kt][0], a0, 0, 0, 0);
            a1 = __builtin_amdgcn_mfma_f32_16x16x32_bf16(A, Bf[kt][1], a1, 0, 0, 0);
        }
        float* o = out + (rowbase + i * 16 + g * 4) * 256 + 32 * w + l16;
        #pragma unroll
        for (int j = 0; j < 4; ++j) {
            o[(long)j * 256 +  0] = a0[j];
            o[(long)j * 256 + 16] = a1[j];
        }

        if (i + 1 < 4) { WRITEC(i + 1) __syncthreads(); }
    }
#undef LOADC
#undef WRITEC
}

// ---------- fallback: verified R1 direct kernel (ws too small) ----------
__global__ __launch_bounds__(1024, 4)
void clements_direct(const float* __restrict__ x,
                     const float* __restrict__ theta,
                     float* __restrict__ out) {
    __shared__ float tbl[NLAYERS * DIM];
    const int tid = threadIdx.x;
    #pragma unroll
    for (int k = 0; k < 8; ++k) {
        int idx = tid + 1024 * k;
        int l = idx >> 7;
        int p = idx & 127;
        float s, c;
        sincosf(2.0f * theta[idx], &s, &c);
        if ((l & 1) && (p == 127)) { c = 1.0f; s = 0.0f; }
        tbl[idx * 2 + 0] = c;
        tbl[idx * 2 + 1] = s;
    }
    __syncthreads();
    const int w = tid >> 6;
    const int t = tid & 63;
    const long base = ((long)blockIdx.x * 16 + w) * 8;
    float e[8][4];
    #pragma unroll
    for (int r = 0; r < 8; ++r) {
        float4 v = ((const float4*)(x + (base + r) * (long)DIM))[t];
        e[r][0] = v.x; e[r][1] = v.y; e[r][2] = v.z; e[r][3] = v.w;
    }
    const float4* tbl4 = (const float4*)tbl;
    #pragma unroll 2
    for (int l = 0; l < NLAYERS; l += 2) {
        float4 cs = tbl4[(l << 6) + t];
        #pragma unroll
        for (int r = 0; r < 8; ++r) {
            float a0 = e[r][0], a1 = e[r][1], a2 = e[r][2], a3 = e[r][3];
            e[r][0] = cs.x * a0 + cs.y * a1;
            e[r][1] = cs.y * a0 - cs.x * a1;
            e[r][2] = cs.z * a2 + cs.w * a3;
            e[r][3] = cs.w * a2 - cs.z * a3;
        }
        float4 cs1 = tbl4[((l + 1) << 6) + t];
        #pragma unroll
        for (int r = 0; r < 8; ++r) {
            float a1 = e[r][1], a2 = e[r][2], a3 = e[r][3];
            float n1 = cs1.x * a1 + cs1.y * a2;
            float n2 = cs1.y * a1 - cs1.x * a2;
            float xjn = dpp_shl1_zero(e[r][0]);
            float n3  = cs1.z * a3 + cs1.w * xjn;
            float snd = cs1.w * a3 - cs1.z * xjn;
            e[r][0] = dpp_shr1_keep(e[r][0], snd);
            e[r][1] = n1; e[r][2] = n2; e[r][3] = n3;
        }
    }
    #pragma unroll
    for (int r = 0; r < 8; ++r) {
        float4 v;
        v.x = e[r][0]; v.y = e[r][1]; v.z = e[r][2]; v.w = e[r][3];
        ((float4*)(out + (base + r) * (long)DIM))[t] = v;
    }
}

extern "C" void kernel_launch(void* const* d_in, const int* in_sizes, int n_in,
                              void* d_out, int out_size, void* d_ws, size_t ws_size,
                              hipStream_t stream) {
    const float* x     = (const float*)d_in[0];
    const float* theta = (const float*)d_in[1];
    float* out = (float*)d_out;

    const size_t need = (size_t)DIM * DIM * sizeof(unsigned short);  // bfrag, 128 KB
    if (ws_size >= need) {
        unsigned short* bfrag = (unsigned short*)d_ws;
        hipLaunchKernelGGL(build_m_kernel, dim3(16),  dim3(1024), 0, stream, theta, bfrag);
        hipLaunchKernelGGL(clements_gemm,  dim3(512), dim3(512),  0, stream, x, bfrag, out);
    } else {
        hipLaunchKernelGGL(clements_direct, dim3(256), dim3(1024), 0, stream, x, theta, out);
    }
}

// Round 7
// 24.051 us; speedup vs baseline: 2.4437x; 1.1117x over previous
//
#include <hip/hip_runtime.h>
#include <math.h>

#define DIM 256
#define NLAYERS 64

typedef __attribute__((ext_vector_type(8))) short short8;
typedef __attribute__((ext_vector_type(4))) float f32x4;

// ---------- helpers ----------
__device__ __forceinline__ float dpp_shl1_zero(float v) {
    int r = __builtin_amdgcn_update_dpp(0, __float_as_int(v), 0x130, 0xF, 0xF, true);
    return __int_as_float(r);
}
__device__ __forceinline__ float dpp_shr1_keep(float oldv, float v) {
    int r = __builtin_amdgcn_update_dpp(__float_as_int(oldv), __float_as_int(v), 0x138, 0xF, 0xF, false);
    return __int_as_float(r);
}
// f32 -> bf16 bits, RNE (cold path: build_m only).
__device__ __forceinline__ unsigned short f2bf(float f) {
    unsigned u = __float_as_uint(f);
    u += 0x7FFFu + ((u >> 16) & 1u);
    return (unsigned short)(u >> 16);
}
// packed f32x2 -> bf16x2 (RNE), single VALU op. No builtin on gfx950 (m240).
__device__ __forceinline__ unsigned cvtpk_bf16(float a, float b) {
    unsigned r;
    asm("v_cvt_pk_bf16_f32 %0, %1, %2" : "=v"(r) : "v"(a), "v"(b));
    return r;
}

// ---------- kernel 1: build M in MFMA-fragment order (bf16) ----------
// 64 blocks x 256 threads (4 waves x 1 identity row). Fast-math trig
// (v_sin/v_cos, ~1e-6 err << bf16 quantization). Row k of M stored at:
//   bfrag[(((col>>4)*8 + (k>>5))*64 + ((k>>3)&3)*16 + (col&15))*8 + (k&7)]
__global__ __launch_bounds__(256)
void build_m_kernel(const float* __restrict__ theta, unsigned short* __restrict__ bfrag) {
    __shared__ float tbl[NLAYERS * DIM];   // 64 KB: [(l*128+p)*2 + {c,s}]
    const int tid = threadIdx.x;
    #pragma unroll 4
    for (int kk = 0; kk < 32; ++kk) {
        int idx = tid + 256 * kk;          // idx = l*128 + p
        int l = idx >> 7, p = idx & 127;
        float a = 2.0f * theta[idx];
        float s = __sinf(a), c = __cosf(a);
        if ((l & 1) && (p == 127)) { c = 1.0f; s = 0.0f; }   // odd-layer passthrough pair
        tbl[idx * 2 + 0] = c;
        tbl[idx * 2 + 1] = s;
    }
    __syncthreads();

    const int w = tid >> 6;
    const int t = tid & 63;
    const int row = blockIdx.x * 4 + w;    // 0..255

    float e[4];
    #pragma unroll
    for (int j = 0; j < 4; ++j) e[j] = (4 * t + j == row) ? 1.0f : 0.0f;

    const float4* tbl4 = (const float4*)tbl;
    #pragma unroll 2
    for (int l = 0; l < NLAYERS; l += 2) {
        float4 cs = tbl4[(l << 6) + t];
        {
            float a0 = e[0], a1 = e[1], a2 = e[2], a3 = e[3];
            e[0] = cs.x * a0 + cs.y * a1;
            e[1] = cs.y * a0 - cs.x * a1;
            e[2] = cs.z * a2 + cs.w * a3;
            e[3] = cs.w * a2 - cs.z * a3;
        }
        float4 cs1 = tbl4[((l + 1) << 6) + t];
        {
            float a1 = e[1], a2 = e[2], a3 = e[3];
            float n1 = cs1.x * a1 + cs1.y * a2;
            float n2 = cs1.y * a1 - cs1.x * a2;
            float xjn = dpp_shl1_zero(e[0]);
            float n3  = cs1.z * a3 + cs1.w * xjn;
            float snd = cs1.w * a3 - cs1.z * xjn;
            e[0] = dpp_shr1_keep(e[0], snd);
            e[1] = n1; e[2] = n2; e[3] = n3;
        }
    }

    const int kt = row >> 5, g8 = (row >> 3) & 3, ki = row & 7;
    #pragma unroll
    for (int j = 0; j < 4; ++j) {
        int col = 4 * t + j;
        bfrag[(((col >> 4) * 8 + kt) * 64 + g8 * 16 + (col & 15)) * 8 + ki] = f2bf(e[j]);
    }
}

// ---------- kernel 2: out = x @ M — global_load_lds + counted-vmcnt pipeline --
// 512 blocks x 512 threads (8 waves); wave w owns output cols [32w,32w+32).
// 64 rows/block = 4 chunks of 16 rows, each in its OWN 16KB LDS buffer (64KB,
// no reuse -> no WAR). Staging: wave w issues 2 global_load_lds_dwordx4 per
// chunk (rows 2w,2w+1; 1KB row per instr). Global source is row-XOR
// pre-swizzled (granule (t&48)|((t^row)&15)) so linear LDS yields conflict-free
// fragment ds_read_b128 (8 rounds = floor). bf16 cvt via v_cvt_pk in compute.
// Gates: counted vmcnt (NEVER 0 mid-kernel) + raw s_barrier (T3/T4):
//   pre-queue B16+ST0..2(6)=22; gate0 vmcnt(4) -> B+ST0 done, ST1,2 in flight.
//   {4,12,18,16} derived with 2 ops/stage, 8 stores/compute left outstanding.
// k enumeration k = kt*32 + 8*(t>>4) + i identical for A and B (hw perm cancels).
// C/D: col=lane&15, row=(lane>>4)*4+reg [m89].
__global__ __launch_bounds__(512, 4)
void clements_gemm(const float* __restrict__ x,
                   const unsigned short* __restrict__ bfrag,
                   float* __restrict__ out) {
    __shared__ float axf[4][16][64][4];    // 64 KB: [chunk][row][granule][4 f32]

    const int tid = threadIdx.x;
    const int w   = tid >> 6;       // wave 0..7
    const int t   = tid & 63;
    const int l16 = t & 15;
    const int g   = t >> 4;         // 0..3
    const long rowbase = (long)blockIdx.x * 64;

    // --- B preload FIRST (16 vmem ops; coalesced 16B/lane from fragment order)
    short8 Bf[8][2];
    {
        const short8* bp = (const short8*)bfrag;
        #pragma unroll
        for (int nt = 0; nt < 2; ++nt)
            #pragma unroll
            for (int kt = 0; kt < 8; ++kt)
                Bf[kt][nt] = bp[((w * 2 + nt) * 8 + kt) * 64 + t];
    }
    asm volatile("" ::: "memory");  // pin B-load issue before the stages

    // per-lane swizzled f32 offsets for this wave's two staged rows
    const int r0 = 2 * w, r1 = 2 * w + 1;
    const int gr0 = ((t & 48) | ((t ^ r0) & 15)) * 4;
    const int gr1 = ((t & 48) | ((t ^ r1) & 15)) * 4;

#define STAGE(i) { \
    const float* g0 = x + (rowbase + (i) * 16 + r0) * 256 + gr0; \
    const float* g1 = x + (rowbase + (i) * 16 + r1) * 256 + gr1; \
    __builtin_amdgcn_global_load_lds((const __attribute__((address_space(1))) void*)g0, \
        (__attribute__((address_space(3))) void*)&axf[i][r0][0][0], 16, 0, 0); \
    __builtin_amdgcn_global_load_lds((const __attribute__((address_space(1))) void*)g1, \
        (__attribute__((address_space(3))) void*)&axf[i][r1][0][0], 16, 0, 0); }

#define GATE(n) { asm volatile("s_waitcnt vmcnt(" #n ")" ::: "memory"); \
                  __builtin_amdgcn_s_barrier(); \
                  __builtin_amdgcn_sched_barrier(0); }

    auto compute = [&](int i) {
        f32x4 a0 = {0.f,0.f,0.f,0.f}, a1 = {0.f,0.f,0.f,0.f};
        #pragma unroll
        for (int kt = 0; kt < 8; ++kt) {
            int j0 = kt * 8 + g * 2;
            int s0 = (j0 & 48) | ((j0 ^ l16) & 15);
            int s1 = ((j0 + 1) & 48) | (((j0 + 1) ^ l16) & 15);
            f32x4 f0 = *(const f32x4*)&axf[i][l16][s0][0];
            f32x4 f1 = *(const f32x4*)&axf[i][l16][s1][0];
            union { short8 s; unsigned u[4]; } A;
            A.u[0] = cvtpk_bf16(f0[0], f0[1]);
            A.u[1] = cvtpk_bf16(f0[2], f0[3]);
            A.u[2] = cvtpk_bf16(f1[0], f1[1]);
            A.u[3] = cvtpk_bf16(f1[2], f1[3]);
            a0 = __builtin_amdgcn_mfma_f32_16x16x32_bf16(A.s, Bf[kt][0], a0, 0, 0, 0);
            a1 = __builtin_amdgcn_mfma_f32_16x16x32_bf16(A.s, Bf[kt][1], a1, 0, 0, 0);
        }
        float* o = out + (rowbase + i * 16 + g * 4) * 256 + 32 * w + l16;
        #pragma unroll
        for (int j = 0; j < 4; ++j) {
            o[(long)j * 256 +  0] = a0[j];
            o[(long)j * 256 + 16] = a1[j];
        }
    };

    STAGE(0) STAGE(1) STAGE(2)

    GATE(4)  STAGE(3) compute(0);
    GATE(12) compute(1);
    GATE(18) compute(2);
    GATE(16) compute(3);
#undef STAGE
#undef GATE
}

// ---------- fallback: verified R1 direct kernel (ws too small) ----------
__global__ __launch_bounds__(1024, 4)
void clements_direct(const float* __restrict__ x,
                     const float* __restrict__ theta,
                     float* __restrict__ out) {
    __shared__ float tbl[NLAYERS * DIM];
    const int tid = threadIdx.x;
    #pragma unroll
    for (int k = 0; k < 8; ++k) {
        int idx = tid + 1024 * k;
        int l = idx >> 7;
        int p = idx & 127;
        float s, c;
        sincosf(2.0f * theta[idx], &s, &c);
        if ((l & 1) && (p == 127)) { c = 1.0f; s = 0.0f; }
        tbl[idx * 2 + 0] = c;
        tbl[idx * 2 + 1] = s;
    }
    __syncthreads();
    const int w = tid >> 6;
    const int t = tid & 63;
    const long base = ((long)blockIdx.x * 16 + w) * 8;
    float e[8][4];
    #pragma unroll
    for (int r = 0; r < 8; ++r) {
        float4 v = ((const float4*)(x + (base + r) * (long)DIM))[t];
        e[r][0] = v.x; e[r][1] = v.y; e[r][2] = v.z; e[r][3] = v.w;
    }
    const float4* tbl4 = (const float4*)tbl;
    #pragma unroll 2
    for (int l = 0; l < NLAYERS; l += 2) {
        float4 cs = tbl4[(l << 6) + t];
        #pragma unroll
        for (int r = 0; r < 8; ++r) {
            float a0 = e[r][0], a1 = e[r][1], a2 = e[r][2], a3 = e[r][3];
            e[r][0] = cs.x * a0 + cs.y * a1;
            e[r][1] = cs.y * a0 - cs.x * a1;
            e[r][2] = cs.z * a2 + cs.w * a3;
            e[r][3] = cs.w * a2 - cs.z * a3;
        }
        float4 cs1 = tbl4[((l + 1) << 6) + t];
        #pragma unroll
        for (int r = 0; r < 8; ++r) {
            float a1 = e[r][1], a2 = e[r][2], a3 = e[r][3];
            float n1 = cs1.x * a1 + cs1.y * a2;
            float n2 = cs1.y * a1 - cs1.x * a2;
            float xjn = dpp_shl1_zero(e[r][0]);
            float n3  = cs1.z * a3 + cs1.w * xjn;
            float snd = cs1.w * a3 - cs1.z * xjn;
            e[r][0] = dpp_shr1_keep(e[r][0], snd);
            e[r][1] = n1; e[r][2] = n2; e[r][3] = n3;
        }
    }
    #pragma unroll
    for (int r = 0; r < 8; ++r) {
        float4 v;
        v.x = e[r][0]; v.y = e[r][1]; v.z = e[r][2]; v.w = e[r][3];
        ((float4*)(out + (base + r) * (long)DIM))[t] = v;
    }
}

extern "C" void kernel_launch(void* const* d_in, const int* in_sizes, int n_in,
                              void* d_out, int out_size, void* d_ws, size_t ws_size,
                              hipStream_t stream) {
    const float* x     = (const float*)d_in[0];
    const float* theta = (const float*)d_in[1];
    float* out = (float*)d_out;

    const size_t need = (size_t)DIM * DIM * sizeof(unsigned short);  // bfrag, 128 KB
    if (ws_size >= need) {
        unsigned short* bfrag = (unsigned short*)d_ws;
        hipLaunchKernelGGL(build_m_kernel, dim3(64),  dim3(256), 0, stream, theta, bfrag);
        hipLaunchKernelGGL(clements_gemm,  dim3(512), dim3(512), 0, stream, x, bfrag, out);
    } else {
        hipLaunchKernelGGL(clements_direct, dim3(256), dim3(1024), 0, stream, x, theta, out);
    }
}